// Round 12
// baseline (776.084 us; speedup 1.0000x reference)
//
#include <hip/hip_runtime.h>
#include <math.h>

// Output layout (floats, concatenated in reference return order)
#define OUT_X      0                  // B*E*T = 8388608
#define OUT_COMMIT 8388608
#define OUT_FIT    8388609
#define OUT_XNORM  8388610
#define OUT_NCB    8388611            // K*E = 131072
#define OUT_NAVG   (8388611 + 131072)
#define OUT_NUSE   (8388611 + 262144) // K = 2048
#define OUT_ENT    (8388611 + 264192)
#define OUT_CBDIFF (8388611 + 264193)

// Workspace layout (bytes) — DACC+COUNTS+CBSUM+BEST contiguous and zeroed
#define WS_DACC    0         // f64[8]: [0]=sum_x [1]=sum_x2 [2]=sum min-dist [4]=diff2
#define WS_COUNTS  64        // u32[2048]
#define WS_CBSUM   8256      // f32[131072]
#define WS_BEST    532544    // u64[131072] packed (mono(val)<<32)|~idx  (zeroed)
#define WS_CURS    1581120   // u32[2048]
#define WS_XN2     1589312   // f32[131072]
#define WS_IDX     2113600   // i32[131072]
#define WS_CN2H    2637888   // f32[2048]  (-0.5*||c||^2)
#define WS_SORTED  2646080   // u32[131072]  packed (k<<17)|n
#define WS_CHI     3170368   // f16[131072]  codebook hi frags
#define WS_CLO     3432512   // f16[131072]  codebook lo frags ((c-hi)*2^5)
#define WS_ZERO_BYTES 1581120
// xt (f32[N][64]) lives in out[OUT_X]: written by prep, read by argmin/
// chunk_reduce/update, overwritten last by kern_out.

#define LO_SCALE5  32.0f              // 2^5 (exact power-of-2 split rebalance)

typedef _Float16 f16x8_t __attribute__((ext_vector_type(8)));
typedef float f32x16_t __attribute__((ext_vector_type(16)));

__device__ __forceinline__ void gload_lds16(const _Float16* g, _Float16* l) {
    __builtin_amdgcn_global_load_lds(
        (const __attribute__((address_space(1))) unsigned int*)(g),
        (__attribute__((address_space(3))) unsigned int*)(l), 16, 0, 0);
}

// ---------- Kernel P: fused transpose+stats (blocks 0-1023) and codebook
//            fragment prep (blocks 1024-1039) --------------------------------
__global__ __launch_bounds__(256) void kern_prep(
    const float* __restrict__ x, float* __restrict__ xt,
    float* __restrict__ xn2, double* __restrict__ dacc,
    const float* __restrict__ cb, _Float16* __restrict__ chi,
    _Float16* __restrict__ clo, float* __restrict__ cn2h)
{
    __shared__ __align__(16) char smem[128 * 68 * 4];   // union: Xs / Cs
    __shared__ float tmpA[4], tmpB[4];
    const int tid = threadIdx.x;
    if (blockIdx.x < 1024) {
        float (*Xs)[128] = (float(*)[128])smem;
        const int n0 = blockIdx.x * 128;
        const int b = n0 >> 12, t0 = n0 & 4095;
        const float* xb = x + ((size_t)b << 18) + t0;
#pragma unroll
        for (int i = 0; i < 8; ++i) {
            int c = i * 256 + tid;
            int e = c >> 5, v4 = c & 31;
            float4 f = *(const float4*)(xb + ((size_t)e << 12) + (v4 << 2));
            *(float4*)&Xs[e][v4 << 2] = f;
        }
        __syncthreads();
        const int q = tid & 3, r0 = tid >> 2;
        float s1t = 0.f, s2t = 0.f;
#pragma unroll
        for (int h = 0; h < 2; ++h) {
            int r = r0 + (h << 6);
            float s2 = 0.f;
#pragma unroll
            for (int j = 0; j < 4; ++j) {
                int e = q * 16 + j * 4;
                float4 f = make_float4(Xs[e][r], Xs[e + 1][r], Xs[e + 2][r], Xs[e + 3][r]);
                *(float4*)(xt + (((size_t)(n0 + r)) << 6) + e) = f;
                s1t += f.x + f.y + f.z + f.w;
                s2 += f.x * f.x + f.y * f.y + f.z * f.z + f.w * f.w;
            }
            s2t += s2;
            float s2q = s2 + __shfl_xor(s2, 1, 64);
            s2q += __shfl_xor(s2q, 2, 64);
            if (q == 0) xn2[n0 + r] = s2q;
        }
        float rs = s1t, r2 = s2t;
#pragma unroll
        for (int m = 32; m >= 1; m >>= 1) {
            rs += __shfl_xor(rs, m, 64);
            r2 += __shfl_xor(r2, m, 64);
        }
        if ((tid & 63) == 0) { tmpA[tid >> 6] = rs; tmpB[tid >> 6] = r2; }
        __syncthreads();
        if (tid == 0) {
            atomicAdd(&dacc[0], (double)(tmpA[0] + tmpA[1] + tmpA[2] + tmpA[3]));
            atomicAdd(&dacc[1], (double)(tmpB[0] + tmpB[1] + tmpB[2] + tmpB[3]));
        }
    } else {
        float (*Cs)[68] = (float(*)[68])smem;
        const int c0 = (blockIdx.x - 1024) * 128;     // 16 blocks
#pragma unroll
        for (int i = 0; i < 8; ++i) {
            int li = i * 256 + tid;
            int code = li >> 4, d4 = li & 15;
            float4 f = *(const float4*)(cb + (((size_t)(c0 + code)) << 6) + (d4 << 2));
            Cs[code][d4 * 4 + 0] = f.x; Cs[code][d4 * 4 + 1] = f.y;
            Cs[code][d4 * 4 + 2] = f.z; Cs[code][d4 * 4 + 3] = f.w;
        }
        __syncthreads();
        const int w = tid >> 6, lane = tid & 63;
        const int cl = (w << 5) + (lane & 31);
        const int g = lane >> 5;
        const int ktg = (blockIdx.x - 1024) * 4 + w;
#pragma unroll
        for (int s = 0; s < 4; ++s) {
            f16x8_t hh, ll;
#pragma unroll
            for (int i = 0; i < 8; ++i) {
                int k = 16 * s + 4 * g + (i & 3) + 8 * (i >> 2);
                float v = Cs[cl][k];
                _Float16 h = (_Float16)v;
                hh[i] = h;
                ll[i] = (_Float16)((v - (float)h) * LO_SCALE5);
            }
            *(f16x8_t*)(chi + (((size_t)(ktg * 4 + s)) << 9) + lane * 8) = hh;
            *(f16x8_t*)(clo + (((size_t)(ktg * 4 + s)) << 9) + lane * 8) = ll;
        }
        if (tid < 128) {
            float s = 0.f;
#pragma unroll
            for (int k = 0; k < 64; ++k) { float v = Cs[tid][k]; s = fmaf(v, v, s); }
            cn2h[c0 + tid] = -0.5f * s;
        }
    }
}

// ---------- Kernel B: octant-resident MFMA distance + packed atomicMax ------
// Grid 1024 = 128 row-groups x 8 octants. Block stages its octant's 256-code
// fragments (64 KB) into LDS ONCE, one barrier, then 4 free-running row
// iterations of 64 rows/wave (2 interleaved acc chains -> dep distance 2).
// Per-row numerics identical to R10/R11:
//   a += ahi*bl + alo5*bh ; a = a*2^-5 + cv ; a += ahi*bh
// Cross-octant merge via atomicMax on (mono(m)<<32 | ~idx): exact, determin-
// istic, tie -> lowest global code index.
__global__ __launch_bounds__(256) void kern_argmin_mfma(
    const float* __restrict__ xt, const float* __restrict__ cn2h,
    const _Float16* __restrict__ chi, const _Float16* __restrict__ clo,
    unsigned long long* __restrict__ bestbuf)
{
    __shared__ __align__(16) _Float16 Bs[8][8][512];   // 64 KB, octant-resident
    const int tid = threadIdx.x;
    const int w = tid >> 6, lane = tid & 63;
    const int l31 = lane & 31, g = lane >> 5;
    const int oct = blockIdx.x & 7;
    const int rg  = blockIdx.x >> 3;

    // stage octant: 64 segs of 1 KB; wave w stages segs j*4+w
#pragma unroll
    for (int j = 0; j < 16; ++j) {
        int seg = (j << 2) | w;
        int tt = seg >> 3, sh = seg & 7;
        const _Float16* src = ((sh & 1) ? clo : chi)
            + ((((size_t)(oct * 8 + tt)) * 4 + (sh >> 1)) << 9) + lane * 8;
        gload_lds16(src, &Bs[tt][sh][0]);
    }
    __syncthreads();   // only barrier in the kernel

    for (int it = 0; it < 4; ++it) {
        const int nw = rg * 1024 + it * 256 + w * 64;
        // A fragments from xt: 2 row-blocks, k = 16s + 4g + {0..3, 8..11}
        f16x8_t ahi[2][4], alo5[2][4];
#pragma unroll
        for (int rb = 0; rb < 2; ++rb) {
            const float* xr = xt + ((size_t)(nw + rb * 32 + l31) << 6) + 4 * g;
#pragma unroll
            for (int s = 0; s < 4; ++s) {
                float4 p = *(const float4*)(xr + 16 * s);
                float4 q = *(const float4*)(xr + 16 * s + 8);
                float vals[8] = {p.x, p.y, p.z, p.w, q.x, q.y, q.z, q.w};
#pragma unroll
                for (int i = 0; i < 8; ++i) {
                    _Float16 h = (_Float16)vals[i];
                    ahi[rb][s][i] = h;
                    alo5[rb][s][i] = (_Float16)((vals[i] - (float)h) * LO_SCALE5);
                }
            }
        }
        float bestm[2][16]; int besti[2][16];
#pragma unroll
        for (int rb = 0; rb < 2; ++rb)
#pragma unroll
            for (int r = 0; r < 16; ++r) { bestm[rb][r] = -INFINITY; besti[rb][r] = 0; }

#pragma unroll
        for (int tt = 0; tt < 8; ++tt) {
            float cv = cn2h[(oct << 8) + (tt << 5) + l31];
            f16x8_t bh[4], bl[4];
#pragma unroll
            for (int s = 0; s < 4; ++s) {
                bh[s] = *(const f16x8_t*)&Bs[tt][s * 2 + 0][lane * 8];
                bl[s] = *(const f16x8_t*)&Bs[tt][s * 2 + 1][lane * 8];
            }
            f32x16_t a0, a1;
#pragma unroll
            for (int r = 0; r < 16; ++r) { a0[r] = 0.f; a1[r] = 0.f; }
            __builtin_amdgcn_s_setprio(1);
#pragma unroll
            for (int s = 0; s < 4; ++s) {
                a0 = __builtin_amdgcn_mfma_f32_32x32x16_f16(ahi[0][s], bl[s], a0, 0, 0, 0);
                a1 = __builtin_amdgcn_mfma_f32_32x32x16_f16(ahi[1][s], bl[s], a1, 0, 0, 0);
            }
#pragma unroll
            for (int s = 0; s < 4; ++s) {
                a0 = __builtin_amdgcn_mfma_f32_32x32x16_f16(alo5[0][s], bh[s], a0, 0, 0, 0);
                a1 = __builtin_amdgcn_mfma_f32_32x32x16_f16(alo5[1][s], bh[s], a1, 0, 0, 0);
            }
#pragma unroll
            for (int r = 0; r < 16; ++r) {
                a0[r] = fmaf(a0[r], 0.03125f, cv);
                a1[r] = fmaf(a1[r], 0.03125f, cv);
            }
#pragma unroll
            for (int s = 0; s < 4; ++s) {
                a0 = __builtin_amdgcn_mfma_f32_32x32x16_f16(ahi[0][s], bh[s], a0, 0, 0, 0);
                a1 = __builtin_amdgcn_mfma_f32_32x32x16_f16(ahi[1][s], bh[s], a1, 0, 0, 0);
            }
            __builtin_amdgcn_s_setprio(0);
#pragma unroll
            for (int r = 0; r < 16; ++r) {
                if (a0[r] > bestm[0][r]) { bestm[0][r] = a0[r]; besti[0][r] = tt; }
                if (a1[r] > bestm[1][r]) { bestm[1][r] = a1[r]; besti[1][r] = tt; }
            }
        }
        // per-iter epilogue: cross-lane argmax over 32 cols, packed atomicMax
#pragma unroll
        for (int rb = 0; rb < 2; ++rb)
#pragma unroll
            for (int r = 0; r < 16; ++r) {
                float mv = bestm[rb][r];
                int mi = (besti[rb][r] << 5) + l31;      // local idx within octant
#pragma unroll
                for (int m = 1; m < 32; m <<= 1) {
                    float ov = __shfl_xor(mv, m, 64);
                    int oi = __shfl_xor(mi, m, 64);
                    if (ov > mv || (ov == mv && oi < mi)) { mv = ov; mi = oi; }
                }
                if (l31 == 0) {
                    int row = (r & 3) + 8 * (r >> 2) + 4 * g;
                    int n = nw + rb * 32 + row;
                    int gidx = (oct << 8) + mi;
                    unsigned bits = __float_as_uint(mv);
                    unsigned mono = bits ^ ((unsigned)((int)bits >> 31) | 0x80000000u);
                    unsigned long long packed =
                        ((unsigned long long)mono << 32) | (unsigned)(~gidx);
                    atomicMax(bestbuf + n, packed);
                }
            }
    }
}

// ---------- Kernel M: merge packed bests -> idxb, counts, fit sum -----------
__global__ __launch_bounds__(256) void kern_merge(
    const unsigned long long* __restrict__ bestbuf, const float* __restrict__ xn2,
    int* __restrict__ idxb, unsigned* __restrict__ counts,
    double* __restrict__ dacc)
{
    __shared__ float tmp[4];
    const int tid = threadIdx.x;
    const int n = blockIdx.x * 256 + tid;   // 512 blocks
    unsigned long long p = bestbuf[n];
    unsigned mono = (unsigned)(p >> 32);
    int gidx = (int)(~(unsigned)(p & 0xFFFFFFFFu));
    unsigned bits = mono ^ ((mono >> 31) ? 0x80000000u : 0xFFFFFFFFu);
    float mv = __uint_as_float(bits);
    idxb[n] = gidx;
    atomicAdd(&counts[gidx], 1u);
    float fs = xn2[n] - 2.f * mv;
#pragma unroll
    for (int m = 32; m >= 1; m >>= 1) fs += __shfl_xor(fs, m, 64);
    if ((tid & 63) == 0) tmp[tid >> 6] = fs;
    __syncthreads();
    if (tid == 0) atomicAdd(&dacc[2], (double)(tmp[0] + tmp[1] + tmp[2] + tmp[3]));
}

// ---------- Kernel S1: exclusive scan of counts -> cursors ------------------
__global__ void kern_scan(const unsigned* __restrict__ counts, unsigned* __restrict__ curs) {
    __shared__ unsigned wtot[4];
    const int tid = threadIdx.x;
    const int base = tid * 8;
    unsigned s[8]; unsigned tot = 0;
#pragma unroll
    for (int j = 0; j < 8; ++j) { s[j] = counts[base + j]; tot += s[j]; }
    unsigned v = tot;
    const int lane = tid & 63;
#pragma unroll
    for (int d = 1; d < 64; d <<= 1) {
        unsigned o = (unsigned)__shfl_up((int)v, d, 64);
        if (lane >= d) v += o;
    }
    if (lane == 63) wtot[tid >> 6] = v;
    __syncthreads();
    unsigned wbase = 0;
    for (int w = 0; w < (tid >> 6); ++w) wbase += wtot[w];
    unsigned run = wbase + v - tot;
#pragma unroll
    for (int j = 0; j < 8; ++j) { curs[base + j] = run; run += s[j]; }
}

// ---------- Kernel S2: scatter packed (code,id) into bins -------------------
__global__ void kern_scatter(const int* __restrict__ idxb, unsigned* __restrict__ curs,
                             unsigned* __restrict__ sorted) {
    const int n = blockIdx.x * 256 + threadIdx.x;   // 512 blocks
    int k = idxb[n];
    unsigned pos = atomicAdd(&curs[k], 1u);
    sorted[pos] = ((unsigned)k << 17) | (unsigned)n;
}

// ---------- Kernel R: chunked segmented reduction -> cb_sum -----------------
__global__ __launch_bounds__(256) void kern_chunk_reduce(
    const float* __restrict__ xt, const unsigned* __restrict__ sorted,
    float* __restrict__ cb_sum)
{
    const int tid = threadIdx.x;
    const int w = tid >> 6, lane = tid & 63;
    const int base = blockIdx.x * 256 + w * 64;
    int kcur = (int)(sorted[base] >> 17);
    float acc = 0.f;
#pragma unroll 4
    for (int it = 0; it < 16; ++it) {
        uint4 p = *(const uint4*)&sorted[base + it * 4];
        float v0 = xt[((size_t)(p.x & 0x1FFFFu) << 6) + lane];
        float v1 = xt[((size_t)(p.y & 0x1FFFFu) << 6) + lane];
        float v2 = xt[((size_t)(p.z & 0x1FFFFu) << 6) + lane];
        float v3 = xt[((size_t)(p.w & 0x1FFFFu) << 6) + lane];
        int k0 = (int)(p.x >> 17), k1 = (int)(p.y >> 17);
        int k2 = (int)(p.z >> 17), k3 = (int)(p.w >> 17);
        if (k0 != kcur) { atomicAdd(&cb_sum[(kcur << 6) + lane], acc); kcur = k0; acc = 0.f; }
        acc += v0;
        if (k1 != kcur) { atomicAdd(&cb_sum[(kcur << 6) + lane], acc); kcur = k1; acc = 0.f; }
        acc += v1;
        if (k2 != kcur) { atomicAdd(&cb_sum[(kcur << 6) + lane], acc); kcur = k2; acc = 0.f; }
        acc += v2;
        if (k3 != kcur) { atomicAdd(&cb_sum[(kcur << 6) + lane], acc); kcur = k3; acc = 0.f; }
        acc += v3;
    }
    atomicAdd(&cb_sum[(kcur << 6) + lane], acc);
}

// ---------- Kernel U: EMA update + keep/replace + diff norm -----------------
__global__ __launch_bounds__(256) void kern_update(
    const float* __restrict__ cb_sum, const unsigned* __restrict__ counts,
    const float* __restrict__ cb, const float* __restrict__ cba,
    const float* __restrict__ usage, const int* __restrict__ perm,
    const float* __restrict__ xt, float* __restrict__ out,
    double* __restrict__ dacc)
{
    const int tid = threadIdx.x;
    const int i = blockIdx.x * 256 + tid;           // 512 blocks
    const int k = i >> 6, e = i & 63;
    float na = 0.99f * cba[i] + 0.01f * cb_sum[i];
    float nu = 0.99f * usage[k] + 0.01f * (float)counts[k];
    float ncb = (nu >= 1.0f) ? (na / nu)
                             : xt[((size_t)perm[k] << 6) + e];
    out[OUT_NAVG + i] = na;
    out[OUT_NCB + i] = ncb;
    if (e == 0) out[OUT_NUSE + k] = nu;
    float d = ncb - cb[i];
    float dd = d * d;
#pragma unroll
    for (int m = 32; m >= 1; m >>= 1) dd += __shfl_xor(dd, m, 64);
    if (e == 0) atomicAdd(&dacc[4], (double)dd);
}

// ---------- Kernel E: scalars (entropy + finalize) --------------------------
// commit = sum min-dist / (N*E) = dacc[2]/8388608 (identical sum to fit).
__global__ void kern_scalars(const unsigned* __restrict__ counts,
                             const double* __restrict__ dacc, float* __restrict__ out) {
    __shared__ float tmp[4];
    __shared__ float totalSh;
    const int tid = threadIdx.x;
    float c = 0.f;
    for (int k = tid; k < 2048; k += 256) c += (float)counts[k];
#pragma unroll
    for (int m = 32; m >= 1; m >>= 1) c += __shfl_xor(c, m, 64);
    if ((tid & 63) == 0) tmp[tid >> 6] = c;
    __syncthreads();
    if (tid == 0) totalSh = tmp[0] + tmp[1] + tmp[2] + tmp[3];
    __syncthreads();
    const float total = totalSh;
    float ent = 0.f;
    for (int k = tid; k < 2048; k += 256) {
        float p = (float)counts[k] / total;
        ent -= p * logf(p + 1e-8f);
    }
#pragma unroll
    for (int m = 32; m >= 1; m >>= 1) ent += __shfl_xor(ent, m, 64);
    __syncthreads();
    if ((tid & 63) == 0) tmp[tid >> 6] = ent;
    __syncthreads();
    if (tid == 0) {
        float entropy = tmp[0] + tmp[1] + tmp[2] + tmp[3];
        out[OUT_COMMIT] = (float)(dacc[2] / 8388608.0);
        out[OUT_FIT]    = (float)(dacc[2] / 131072.0);
        double nd = 8388608.0;
        double var = dacc[1] - dacc[0] * dacc[0] / nd;
        if (var < 0.0) var = 0.0;
        out[OUT_XNORM] = (float)(sqrt(var) / sqrt(nd));
        out[OUT_ENT] = entropy;
        out[OUT_CBDIFF] = (float)(sqrt(dacc[4]) / sqrt(131072.0));
    }
}

// ---------- Kernel C: pure gather q -> out (out = q exactly) ----------------
__global__ __launch_bounds__(256) void kern_out(
    const float* __restrict__ cb, const int* __restrict__ idxb,
    float* __restrict__ out) {
    const int tid = threadIdx.x;
    const int n0 = blockIdx.x * 256 + (tid & 63) * 4;   // 512 blocks
    const int ec = tid >> 6;
    const int b = n0 >> 12, t = n0 & 4095;
    int4 k4 = *(const int4*)(idxb + n0);
    float* ob = out + OUT_X + ((size_t)b << 18) + t;
#pragma unroll
    for (int j = 0; j < 16; ++j) {
        int e = ec * 16 + j;
        float q0 = cb[((size_t)k4.x << 6) + e], q1 = cb[((size_t)k4.y << 6) + e];
        float q2 = cb[((size_t)k4.z << 6) + e], q3 = cb[((size_t)k4.w << 6) + e];
        *(float4*)(ob + ((size_t)e << 12)) = make_float4(q0, q1, q2, q3);
    }
}

extern "C" void kernel_launch(void* const* d_in, const int* in_sizes, int n_in,
                              void* d_out, int out_size, void* d_ws, size_t ws_size,
                              hipStream_t stream) {
    const float* x     = (const float*)d_in[0];
    const float* cb    = (const float*)d_in[1];
    const float* cba   = (const float*)d_in[2];
    const float* usage = (const float*)d_in[3];
    const int*   perm  = (const int*)d_in[4];
    float* out = (float*)d_out;
    char* ws = (char*)d_ws;
    double*             dacc    = (double*)(ws + WS_DACC);
    unsigned*           counts  = (unsigned*)(ws + WS_COUNTS);
    float*              cbsum   = (float*)(ws + WS_CBSUM);
    unsigned long long* bestbuf = (unsigned long long*)(ws + WS_BEST);
    unsigned*           curs    = (unsigned*)(ws + WS_CURS);
    float*              xn2     = (float*)(ws + WS_XN2);
    int*                idxb    = (int*)(ws + WS_IDX);
    float*              cn2h    = (float*)(ws + WS_CN2H);
    unsigned*           sorted  = (unsigned*)(ws + WS_SORTED);
    _Float16*           chi     = (_Float16*)(ws + WS_CHI);
    _Float16*           clo     = (_Float16*)(ws + WS_CLO);
    float*              xt      = out + OUT_X;   // staged; overwritten last by kern_out

    hipMemsetAsync(ws, 0, WS_ZERO_BYTES, stream);
    kern_prep<<<1040, 256, 0, stream>>>(x, xt, xn2, dacc, cb, chi, clo, cn2h);
    kern_argmin_mfma<<<1024, 256, 0, stream>>>(xt, cn2h, chi, clo, bestbuf);
    kern_merge<<<512, 256, 0, stream>>>(bestbuf, xn2, idxb, counts, dacc);
    kern_scan<<<1, 256, 0, stream>>>(counts, curs);
    kern_scatter<<<512, 256, 0, stream>>>(idxb, curs, sorted);
    kern_chunk_reduce<<<512, 256, 0, stream>>>(xt, sorted, cbsum);
    kern_update<<<512, 256, 0, stream>>>(cbsum, counts, cb, cba, usage, perm, xt, out, dacc);
    kern_scalars<<<1, 256, 0, stream>>>(counts, dacc, out);
    kern_out<<<512, 256, 0, stream>>>(cb, idxb, out);
}

// Round 13
// 396.570 us; speedup vs baseline: 1.9570x; 1.9570x over previous
//
#include <hip/hip_runtime.h>
#include <math.h>

// Output layout (floats, concatenated in reference return order)
#define OUT_X      0                  // B*E*T = 8388608
#define OUT_COMMIT 8388608
#define OUT_FIT    8388609
#define OUT_XNORM  8388610
#define OUT_NCB    8388611            // K*E = 131072
#define OUT_NAVG   (8388611 + 131072)
#define OUT_NUSE   (8388611 + 262144) // K = 2048
#define OUT_ENT    (8388611 + 264192)
#define OUT_CBDIFF (8388611 + 264193)

// Workspace layout (bytes) — DACC+COUNTS+CBSUM contiguous and zeroed
#define WS_DACC    0         // f64[8]: [0]=sum_x [1]=sum_x2 [2]=sum min-dist [4]=diff2
#define WS_COUNTS  64        // u32[2048]
#define WS_CBSUM   8256      // f32[131072]
#define WS_CURS    532544    // u32[2048]
#define WS_XN2     540736    // f32[131072]
#define WS_IDX     1065024   // i32[131072]
#define WS_CN2H    1589312   // f32[2048]  (-0.5*||c||^2)
#define WS_SORTED  1597504   // u32[131072]  packed (k<<17)|n
#define WS_CHI     2121792   // f16[131072]  codebook hi frags
#define WS_CLO     2383936   // f16[131072]  codebook lo frags ((c-hi)*2^5)
#define WS_ZERO_BYTES 532544
// xt (f32[N][64]) lives in out[OUT_X]: written by prep, read by argmin/
// chunk_reduce/update, overwritten last by kern_out.

#define LO_SCALE5  32.0f              // 2^5 (exact power-of-2 split rebalance)

typedef _Float16 f16x8_t __attribute__((ext_vector_type(8)));
typedef float f32x16_t __attribute__((ext_vector_type(16)));

__device__ __forceinline__ void gload_lds16(const _Float16* g, _Float16* l) {
    __builtin_amdgcn_global_load_lds(
        (const __attribute__((address_space(1))) unsigned int*)(g),
        (__attribute__((address_space(3))) unsigned int*)(l), 16, 0, 0);
}

// ---------- Kernel P: fused transpose+stats (blocks 0-1023) and codebook
//            fragment prep (blocks 1024-1039) --------------------------------
__global__ __launch_bounds__(256) void kern_prep(
    const float* __restrict__ x, float* __restrict__ xt,
    float* __restrict__ xn2, double* __restrict__ dacc,
    const float* __restrict__ cb, _Float16* __restrict__ chi,
    _Float16* __restrict__ clo, float* __restrict__ cn2h)
{
    __shared__ __align__(16) char smem[128 * 68 * 4];   // union: Xs / Cs
    __shared__ float tmpA[4], tmpB[4];
    const int tid = threadIdx.x;
    if (blockIdx.x < 1024) {
        float (*Xs)[128] = (float(*)[128])smem;
        const int n0 = blockIdx.x * 128;
        const int b = n0 >> 12, t0 = n0 & 4095;
        const float* xb = x + ((size_t)b << 18) + t0;
#pragma unroll
        for (int i = 0; i < 8; ++i) {
            int c = i * 256 + tid;
            int e = c >> 5, v4 = c & 31;
            float4 f = *(const float4*)(xb + ((size_t)e << 12) + (v4 << 2));
            *(float4*)&Xs[e][v4 << 2] = f;
        }
        __syncthreads();
        const int q = tid & 3, r0 = tid >> 2;
        float s1t = 0.f, s2t = 0.f;
#pragma unroll
        for (int h = 0; h < 2; ++h) {
            int r = r0 + (h << 6);
            float s2 = 0.f;
#pragma unroll
            for (int j = 0; j < 4; ++j) {
                int e = q * 16 + j * 4;
                float4 f = make_float4(Xs[e][r], Xs[e + 1][r], Xs[e + 2][r], Xs[e + 3][r]);
                *(float4*)(xt + (((size_t)(n0 + r)) << 6) + e) = f;
                s1t += f.x + f.y + f.z + f.w;
                s2 += f.x * f.x + f.y * f.y + f.z * f.z + f.w * f.w;
            }
            s2t += s2;
            float s2q = s2 + __shfl_xor(s2, 1, 64);
            s2q += __shfl_xor(s2q, 2, 64);
            if (q == 0) xn2[n0 + r] = s2q;
        }
        float rs = s1t, r2 = s2t;
#pragma unroll
        for (int m = 32; m >= 1; m >>= 1) {
            rs += __shfl_xor(rs, m, 64);
            r2 += __shfl_xor(r2, m, 64);
        }
        if ((tid & 63) == 0) { tmpA[tid >> 6] = rs; tmpB[tid >> 6] = r2; }
        __syncthreads();
        if (tid == 0) {
            atomicAdd(&dacc[0], (double)(tmpA[0] + tmpA[1] + tmpA[2] + tmpA[3]));
            atomicAdd(&dacc[1], (double)(tmpB[0] + tmpB[1] + tmpB[2] + tmpB[3]));
        }
    } else {
        float (*Cs)[68] = (float(*)[68])smem;
        const int c0 = (blockIdx.x - 1024) * 128;     // 16 blocks
#pragma unroll
        for (int i = 0; i < 8; ++i) {
            int li = i * 256 + tid;
            int code = li >> 4, d4 = li & 15;
            float4 f = *(const float4*)(cb + (((size_t)(c0 + code)) << 6) + (d4 << 2));
            Cs[code][d4 * 4 + 0] = f.x; Cs[code][d4 * 4 + 1] = f.y;
            Cs[code][d4 * 4 + 2] = f.z; Cs[code][d4 * 4 + 3] = f.w;
        }
        __syncthreads();
        const int w = tid >> 6, lane = tid & 63;
        const int cl = (w << 5) + (lane & 31);
        const int g = lane >> 5;
        const int ktg = (blockIdx.x - 1024) * 4 + w;
#pragma unroll
        for (int s = 0; s < 4; ++s) {
            f16x8_t hh, ll;
#pragma unroll
            for (int i = 0; i < 8; ++i) {
                int k = 16 * s + 4 * g + (i & 3) + 8 * (i >> 2);
                float v = Cs[cl][k];
                _Float16 h = (_Float16)v;
                hh[i] = h;
                ll[i] = (_Float16)((v - (float)h) * LO_SCALE5);
            }
            *(f16x8_t*)(chi + (((size_t)(ktg * 4 + s)) << 9) + lane * 8) = hh;
            *(f16x8_t*)(clo + (((size_t)(ktg * 4 + s)) << 9) + lane * 8) = ll;
        }
        if (tid < 128) {
            float s = 0.f;
#pragma unroll
            for (int k = 0; k < 64; ++k) { float v = Cs[tid][k]; s = fmaf(v, v, s); }
            cn2h[c0 + tid] = -0.5f * s;
        }
    }
}

// ---------- Kernel B: MFMA distance + argmax(m) + counts (R6 structure) -----
// m = cv + sum ahi*bh + 2^-5 * [sum alo5*bh + sum ahi*bl5]   (cv = -0.5||c||^2)
// 4 blocks/CU (40 KB LDS), 4 waves/SIMD; 2-slot ring, vmcnt(0)+s_barrier per
// phase (1-phase lookahead), loop unrolled x2 so ring slots are static.
__global__ __launch_bounds__(256, 4) void kern_argmin_mfma(
    const float* __restrict__ xt, const float* __restrict__ cn2h,
    const _Float16* __restrict__ chi, const _Float16* __restrict__ clo,
    const float* __restrict__ xn2, int* __restrict__ idxb,
    unsigned* __restrict__ counts, double* __restrict__ dacc)
{
    __shared__ __align__(16) _Float16 Bs[2][2][8][512];  // 32 KB ring
    __shared__ float cvs[2048];                          // 8 KB (-0.5*||c||^2)
    const int tid = threadIdx.x;
    const int w = tid >> 6, lane = tid & 63;
    const int n0 = blockIdx.x * 128 + w * 32;            // 1024 blocks
    const int l31 = lane & 31, g = lane >> 5;

    for (int i = tid; i < 2048; i += 256) cvs[i] = cn2h[i];

    // A fragments from xt: k = 16s + 4g + {0..3, 8..11}
    f16x8_t ahi[4], alo5[4];
    {
        const float* xr = xt + ((size_t)(n0 + l31) << 6) + 4 * g;
#pragma unroll
        for (int s = 0; s < 4; ++s) {
            float4 p = *(const float4*)(xr + 16 * s);
            float4 q = *(const float4*)(xr + 16 * s + 8);
            float vals[8] = {p.x, p.y, p.z, p.w, q.x, q.y, q.z, q.w};
#pragma unroll
            for (int i = 0; i < 8; ++i) {
                _Float16 h = (_Float16)vals[i];
                ahi[s][i] = h;
                alo5[s][i] = (_Float16)((vals[i] - (float)h) * LO_SCALE5);
            }
        }
    }
    float bestm[16]; int besti[16];
#pragma unroll
    for (int r = 0; r < 16; ++r) { bestm[r] = -INFINITY; besti[r] = 0; }

#define STAGE(kt_, slot_) do {                                               \
    _Pragma("unroll")                                                        \
    for (int j = 0; j < 4; ++j) {                                            \
        int seg = (j << 2) | w;                                              \
        int tt_ = seg >> 3, sh_ = seg & 7;                                   \
        const _Float16* src = ((sh_ & 1) ? clo : chi)                        \
            + ((((size_t)((kt_) * 2 + tt_)) * 4 + (sh_ >> 1)) << 9) + lane * 8; \
        gload_lds16(src, &Bs[slot_][tt_][sh_][0]);                           \
    }                                                                        \
} while (0)

#define PHASE(kt_, cs_) do {                                                 \
    asm volatile("s_waitcnt vmcnt(0)" ::: "memory");                         \
    __builtin_amdgcn_s_barrier();                                            \
    if ((kt_) + 1 < 32) STAGE((kt_) + 1, (cs_) ^ 1);                         \
    _Pragma("unroll")                                                        \
    for (int tt = 0; tt < 2; ++tt) {                                         \
        const int tg = (kt_) * 2 + tt;                                       \
        float cv = cvs[(tg << 5) + l31];                                     \
        f32x16_t am, ac;                                                     \
        _Pragma("unroll")                                                    \
        for (int r = 0; r < 16; ++r) { am[r] = cv; ac[r] = 0.f; }            \
        _Pragma("unroll")                                                    \
        for (int s = 0; s < 4; ++s) {                                        \
            f16x8_t bh = *(const f16x8_t*)&Bs[cs_][tt][s * 2 + 0][lane * 8]; \
            f16x8_t bl = *(const f16x8_t*)&Bs[cs_][tt][s * 2 + 1][lane * 8]; \
            am = __builtin_amdgcn_mfma_f32_32x32x16_f16(ahi[s],  bh, am, 0, 0, 0); \
            ac = __builtin_amdgcn_mfma_f32_32x32x16_f16(alo5[s], bh, ac, 0, 0, 0); \
            ac = __builtin_amdgcn_mfma_f32_32x32x16_f16(ahi[s],  bl, ac, 0, 0, 0); \
        }                                                                    \
        _Pragma("unroll")                                                    \
        for (int r = 0; r < 16; ++r) {                                       \
            float m = fmaf(0.03125f, ac[r], am[r]);                          \
            if (m > bestm[r]) { bestm[r] = m; besti[r] = tg; }               \
        }                                                                    \
    }                                                                        \
} while (0)

    STAGE(0, 0);
    __syncthreads();   // cvs visible + phase-0 staging complete (full drain)

    for (int kt = 0; kt < 32; kt += 2) {
        PHASE(kt, 0);
        PHASE(kt + 1, 1);
    }
#undef STAGE
#undef PHASE

    // cross-lane argmax over the 32 codes (within each 32-lane half)
    float fs = 0.f;
#pragma unroll
    for (int r = 0; r < 16; ++r) {
        float mv = bestm[r]; int mi = (besti[r] << 5) + l31;
#pragma unroll
        for (int m = 1; m < 32; m <<= 1) {
            float ov = __shfl_xor(mv, m, 64);
            int oi = __shfl_xor(mi, m, 64);
            if (ov > mv || (ov == mv && oi < mi)) { mv = ov; mi = oi; }
        }
        if (l31 == 0) {
            int row = (r & 3) + 8 * (r >> 2) + 4 * g;
            int n = n0 + row;
            idxb[n] = mi;
            atomicAdd(&counts[mi], 1u);
            fs += xn2[n] - 2.f * mv;
        }
    }
    if (l31 == 0) atomicAdd(&dacc[2], (double)fs);
}

// ---------- Kernel S1: exclusive scan of counts -> cursors ------------------
__global__ void kern_scan(const unsigned* __restrict__ counts, unsigned* __restrict__ curs) {
    __shared__ unsigned wtot[4];
    const int tid = threadIdx.x;
    const int base = tid * 8;
    unsigned s[8]; unsigned tot = 0;
#pragma unroll
    for (int j = 0; j < 8; ++j) { s[j] = counts[base + j]; tot += s[j]; }
    unsigned v = tot;
    const int lane = tid & 63;
#pragma unroll
    for (int d = 1; d < 64; d <<= 1) {
        unsigned o = (unsigned)__shfl_up((int)v, d, 64);
        if (lane >= d) v += o;
    }
    if (lane == 63) wtot[tid >> 6] = v;
    __syncthreads();
    unsigned wbase = 0;
    for (int w = 0; w < (tid >> 6); ++w) wbase += wtot[w];
    unsigned run = wbase + v - tot;
#pragma unroll
    for (int j = 0; j < 8; ++j) { curs[base + j] = run; run += s[j]; }
}

// ---------- Kernel S2: scatter packed (code,id) into bins -------------------
__global__ void kern_scatter(const int* __restrict__ idxb, unsigned* __restrict__ curs,
                             unsigned* __restrict__ sorted) {
    const int n = blockIdx.x * 256 + threadIdx.x;   // 512 blocks
    int k = idxb[n];
    unsigned pos = atomicAdd(&curs[k], 1u);
    sorted[pos] = ((unsigned)k << 17) | (unsigned)n;
}

// ---------- Kernel R: chunked segmented reduction -> cb_sum -----------------
__global__ __launch_bounds__(256) void kern_chunk_reduce(
    const float* __restrict__ xt, const unsigned* __restrict__ sorted,
    float* __restrict__ cb_sum)
{
    const int tid = threadIdx.x;
    const int w = tid >> 6, lane = tid & 63;
    const int base = blockIdx.x * 256 + w * 64;
    int kcur = (int)(sorted[base] >> 17);
    float acc = 0.f;
#pragma unroll 4
    for (int it = 0; it < 16; ++it) {
        uint4 p = *(const uint4*)&sorted[base + it * 4];
        float v0 = xt[((size_t)(p.x & 0x1FFFFu) << 6) + lane];
        float v1 = xt[((size_t)(p.y & 0x1FFFFu) << 6) + lane];
        float v2 = xt[((size_t)(p.z & 0x1FFFFu) << 6) + lane];
        float v3 = xt[((size_t)(p.w & 0x1FFFFu) << 6) + lane];
        int k0 = (int)(p.x >> 17), k1 = (int)(p.y >> 17);
        int k2 = (int)(p.z >> 17), k3 = (int)(p.w >> 17);
        if (k0 != kcur) { atomicAdd(&cb_sum[(kcur << 6) + lane], acc); kcur = k0; acc = 0.f; }
        acc += v0;
        if (k1 != kcur) { atomicAdd(&cb_sum[(kcur << 6) + lane], acc); kcur = k1; acc = 0.f; }
        acc += v1;
        if (k2 != kcur) { atomicAdd(&cb_sum[(kcur << 6) + lane], acc); kcur = k2; acc = 0.f; }
        acc += v2;
        if (k3 != kcur) { atomicAdd(&cb_sum[(kcur << 6) + lane], acc); kcur = k3; acc = 0.f; }
        acc += v3;
    }
    atomicAdd(&cb_sum[(kcur << 6) + lane], acc);
}

// ---------- Kernel U: EMA update + keep/replace + diff norm -----------------
__global__ __launch_bounds__(256) void kern_update(
    const float* __restrict__ cb_sum, const unsigned* __restrict__ counts,
    const float* __restrict__ cb, const float* __restrict__ cba,
    const float* __restrict__ usage, const int* __restrict__ perm,
    const float* __restrict__ xt, float* __restrict__ out,
    double* __restrict__ dacc)
{
    const int tid = threadIdx.x;
    const int i = blockIdx.x * 256 + tid;           // 512 blocks
    const int k = i >> 6, e = i & 63;
    float na = 0.99f * cba[i] + 0.01f * cb_sum[i];
    float nu = 0.99f * usage[k] + 0.01f * (float)counts[k];
    float ncb = (nu >= 1.0f) ? (na / nu)
                             : xt[((size_t)perm[k] << 6) + e];
    out[OUT_NAVG + i] = na;
    out[OUT_NCB + i] = ncb;
    if (e == 0) out[OUT_NUSE + k] = nu;
    float d = ncb - cb[i];
    float dd = d * d;
#pragma unroll
    for (int m = 32; m >= 1; m >>= 1) dd += __shfl_xor(dd, m, 64);
    if (e == 0) atomicAdd(&dacc[4], (double)dd);
}

// ---------- Kernel E: scalars (entropy + finalize) --------------------------
// commit = sum min-dist / (N*E) = dacc[2]/8388608 (identical sum to fit).
__global__ void kern_scalars(const unsigned* __restrict__ counts,
                             const double* __restrict__ dacc, float* __restrict__ out) {
    __shared__ float tmp[4];
    __shared__ float totalSh;
    const int tid = threadIdx.x;
    float c = 0.f;
    for (int k = tid; k < 2048; k += 256) c += (float)counts[k];
#pragma unroll
    for (int m = 32; m >= 1; m >>= 1) c += __shfl_xor(c, m, 64);
    if ((tid & 63) == 0) tmp[tid >> 6] = c;
    __syncthreads();
    if (tid == 0) totalSh = tmp[0] + tmp[1] + tmp[2] + tmp[3];
    __syncthreads();
    const float total = totalSh;
    float ent = 0.f;
    for (int k = tid; k < 2048; k += 256) {
        float p = (float)counts[k] / total;
        ent -= p * logf(p + 1e-8f);
    }
#pragma unroll
    for (int m = 32; m >= 1; m >>= 1) ent += __shfl_xor(ent, m, 64);
    __syncthreads();
    if ((tid & 63) == 0) tmp[tid >> 6] = ent;
    __syncthreads();
    if (tid == 0) {
        float entropy = tmp[0] + tmp[1] + tmp[2] + tmp[3];
        out[OUT_COMMIT] = (float)(dacc[2] / 8388608.0);
        out[OUT_FIT]    = (float)(dacc[2] / 131072.0);
        double nd = 8388608.0;
        double var = dacc[1] - dacc[0] * dacc[0] / nd;
        if (var < 0.0) var = 0.0;
        out[OUT_XNORM] = (float)(sqrt(var) / sqrt(nd));
        out[OUT_ENT] = entropy;
        out[OUT_CBDIFF] = (float)(sqrt(dacc[4]) / sqrt(131072.0));
    }
}

// ---------- Kernel C: pure gather q -> out (out = q exactly) ----------------
__global__ __launch_bounds__(256) void kern_out(
    const float* __restrict__ cb, const int* __restrict__ idxb,
    float* __restrict__ out) {
    const int tid = threadIdx.x;
    const int n0 = blockIdx.x * 256 + (tid & 63) * 4;   // 512 blocks
    const int ec = tid >> 6;
    const int b = n0 >> 12, t = n0 & 4095;
    int4 k4 = *(const int4*)(idxb + n0);
    float* ob = out + OUT_X + ((size_t)b << 18) + t;
#pragma unroll
    for (int j = 0; j < 16; ++j) {
        int e = ec * 16 + j;
        float q0 = cb[((size_t)k4.x << 6) + e], q1 = cb[((size_t)k4.y << 6) + e];
        float q2 = cb[((size_t)k4.z << 6) + e], q3 = cb[((size_t)k4.w << 6) + e];
        *(float4*)(ob + ((size_t)e << 12)) = make_float4(q0, q1, q2, q3);
    }
}

extern "C" void kernel_launch(void* const* d_in, const int* in_sizes, int n_in,
                              void* d_out, int out_size, void* d_ws, size_t ws_size,
                              hipStream_t stream) {
    const float* x     = (const float*)d_in[0];
    const float* cb    = (const float*)d_in[1];
    const float* cba   = (const float*)d_in[2];
    const float* usage = (const float*)d_in[3];
    const int*   perm  = (const int*)d_in[4];
    float* out = (float*)d_out;
    char* ws = (char*)d_ws;
    double*    dacc   = (double*)(ws + WS_DACC);
    unsigned*  counts = (unsigned*)(ws + WS_COUNTS);
    float*     cbsum  = (float*)(ws + WS_CBSUM);
    unsigned*  curs   = (unsigned*)(ws + WS_CURS);
    float*     xn2    = (float*)(ws + WS_XN2);
    int*       idxb   = (int*)(ws + WS_IDX);
    float*     cn2h   = (float*)(ws + WS_CN2H);
    unsigned*  sorted = (unsigned*)(ws + WS_SORTED);
    _Float16*  chi    = (_Float16*)(ws + WS_CHI);
    _Float16*  clo    = (_Float16*)(ws + WS_CLO);
    float*     xt     = out + OUT_X;   // staged; overwritten last by kern_out

    hipMemsetAsync(ws, 0, WS_ZERO_BYTES, stream);
    kern_prep<<<1040, 256, 0, stream>>>(x, xt, xn2, dacc, cb, chi, clo, cn2h);
    kern_argmin_mfma<<<1024, 256, 0, stream>>>(xt, cn2h, chi, clo, xn2, idxb, counts, dacc);
    kern_scan<<<1, 256, 0, stream>>>(counts, curs);
    kern_scatter<<<512, 256, 0, stream>>>(idxb, curs, sorted);
    kern_chunk_reduce<<<512, 256, 0, stream>>>(xt, sorted, cbsum);
    kern_update<<<512, 256, 0, stream>>>(cbsum, counts, cb, cba, usage, perm, xt, out, dacc);
    kern_scalars<<<1, 256, 0, stream>>>(counts, dacc, out);
    kern_out<<<512, 256, 0, stream>>>(cb, idxb, out);
}

// Round 14
// 273.531 us; speedup vs baseline: 2.8373x; 1.4498x over previous
//
#include <hip/hip_runtime.h>
#include <math.h>

// Output layout (floats, concatenated in reference return order)
#define OUT_X      0                  // B*E*T = 8388608
#define OUT_COMMIT 8388608
#define OUT_FIT    8388609
#define OUT_XNORM  8388610
#define OUT_NCB    8388611            // K*E = 131072
#define OUT_NAVG   (8388611 + 131072)
#define OUT_NUSE   (8388611 + 262144) // K = 2048
#define OUT_ENT    (8388611 + 264192)
#define OUT_CBDIFF (8388611 + 264193)

// Workspace layout (bytes) — DACC+COUNTS+CBSUM contiguous and zeroed
#define WS_DACC    0         // f64[8]: [0]=sum_x [1]=sum_x2 [2]=sum min-dist [4]=diff2
#define WS_COUNTS  64        // u32[2048]
#define WS_CBSUM   8256      // f32[131072]
#define WS_CURS    532544    // u32[2048]
#define WS_XN2     540736    // f32[131072]
#define WS_IDX     1065024   // i32[131072]
#define WS_CN2H    1589312   // f32[2048]  (-0.5*||c||^2)
#define WS_SORTED  1597504   // u32[131072]  packed (k<<17)|n
#define WS_CHI     2121792   // f16[131072]  codebook hi frags
#define WS_CLO     2383936   // f16[131072]  codebook lo frags ((c-hi)*2^5)
#define WS_ZERO_BYTES 532544
// xt (f32[N][64]) lives in out[OUT_X]: written by prep, read by argmin/
// chunk_reduce/update, overwritten last by kern_out.

#define LO_SCALE5  32.0f              // 2^5 (exact power-of-2 split rebalance)

typedef _Float16 f16x8_t __attribute__((ext_vector_type(8)));
typedef float f32x16_t __attribute__((ext_vector_type(16)));

__device__ __forceinline__ void gload_lds16(const _Float16* g, _Float16* l) {
    __builtin_amdgcn_global_load_lds(
        (const __attribute__((address_space(1))) unsigned int*)(g),
        (__attribute__((address_space(3))) unsigned int*)(l), 16, 0, 0);
}

// ---------- Kernel P: fused transpose+stats (blocks 0-1023) and codebook
//            fragment prep (blocks 1024-1039) --------------------------------
__global__ __launch_bounds__(256) void kern_prep(
    const float* __restrict__ x, float* __restrict__ xt,
    float* __restrict__ xn2, double* __restrict__ dacc,
    const float* __restrict__ cb, _Float16* __restrict__ chi,
    _Float16* __restrict__ clo, float* __restrict__ cn2h)
{
    __shared__ __align__(16) char smem[128 * 68 * 4];   // union: Xs / Cs
    __shared__ float tmpA[4], tmpB[4];
    const int tid = threadIdx.x;
    if (blockIdx.x < 1024) {
        float (*Xs)[128] = (float(*)[128])smem;
        const int n0 = blockIdx.x * 128;
        const int b = n0 >> 12, t0 = n0 & 4095;
        const float* xb = x + ((size_t)b << 18) + t0;
#pragma unroll
        for (int i = 0; i < 8; ++i) {
            int c = i * 256 + tid;
            int e = c >> 5, v4 = c & 31;
            float4 f = *(const float4*)(xb + ((size_t)e << 12) + (v4 << 2));
            *(float4*)&Xs[e][v4 << 2] = f;
        }
        __syncthreads();
        const int q = tid & 3, r0 = tid >> 2;
        float s1t = 0.f, s2t = 0.f;
#pragma unroll
        for (int h = 0; h < 2; ++h) {
            int r = r0 + (h << 6);
            float s2 = 0.f;
#pragma unroll
            for (int j = 0; j < 4; ++j) {
                int e = q * 16 + j * 4;
                float4 f = make_float4(Xs[e][r], Xs[e + 1][r], Xs[e + 2][r], Xs[e + 3][r]);
                *(float4*)(xt + (((size_t)(n0 + r)) << 6) + e) = f;
                s1t += f.x + f.y + f.z + f.w;
                s2 += f.x * f.x + f.y * f.y + f.z * f.z + f.w * f.w;
            }
            s2t += s2;
            float s2q = s2 + __shfl_xor(s2, 1, 64);
            s2q += __shfl_xor(s2q, 2, 64);
            if (q == 0) xn2[n0 + r] = s2q;
        }
        float rs = s1t, r2 = s2t;
#pragma unroll
        for (int m = 32; m >= 1; m >>= 1) {
            rs += __shfl_xor(rs, m, 64);
            r2 += __shfl_xor(r2, m, 64);
        }
        if ((tid & 63) == 0) { tmpA[tid >> 6] = rs; tmpB[tid >> 6] = r2; }
        __syncthreads();
        if (tid == 0) {
            atomicAdd(&dacc[0], (double)(tmpA[0] + tmpA[1] + tmpA[2] + tmpA[3]));
            atomicAdd(&dacc[1], (double)(tmpB[0] + tmpB[1] + tmpB[2] + tmpB[3]));
        }
    } else {
        float (*Cs)[68] = (float(*)[68])smem;
        const int c0 = (blockIdx.x - 1024) * 128;     // 16 blocks
#pragma unroll
        for (int i = 0; i < 8; ++i) {
            int li = i * 256 + tid;
            int code = li >> 4, d4 = li & 15;
            float4 f = *(const float4*)(cb + (((size_t)(c0 + code)) << 6) + (d4 << 2));
            Cs[code][d4 * 4 + 0] = f.x; Cs[code][d4 * 4 + 1] = f.y;
            Cs[code][d4 * 4 + 2] = f.z; Cs[code][d4 * 4 + 3] = f.w;
        }
        __syncthreads();
        const int w = tid >> 6, lane = tid & 63;
        const int cl = (w << 5) + (lane & 31);
        const int g = lane >> 5;
        const int ktg = (blockIdx.x - 1024) * 4 + w;
#pragma unroll
        for (int s = 0; s < 4; ++s) {
            f16x8_t hh, ll;
#pragma unroll
            for (int i = 0; i < 8; ++i) {
                int k = 16 * s + 4 * g + (i & 3) + 8 * (i >> 2);
                float v = Cs[cl][k];
                _Float16 h = (_Float16)v;
                hh[i] = h;
                ll[i] = (_Float16)((v - (float)h) * LO_SCALE5);
            }
            *(f16x8_t*)(chi + (((size_t)(ktg * 4 + s)) << 9) + lane * 8) = hh;
            *(f16x8_t*)(clo + (((size_t)(ktg * 4 + s)) << 9) + lane * 8) = ll;
        }
        if (tid < 128) {
            float s = 0.f;
#pragma unroll
            for (int k = 0; k < 64; ++k) { float v = Cs[tid][k]; s = fmaf(v, v, s); }
            cn2h[c0 + tid] = -0.5f * s;
        }
    }
}

// ---------- Kernel B: MFMA distance + argmax(m) + counts --------------------
// VERBATIM the Round-6 bench kernel (165 us, VGPR 124, no spill):
// m = cv + ahi*bh + (alo*2^5)*(bh*2^-5) + (ahi*2^-5)*(bl*2^5); 64 vectors/
// wave (2 row-blocks share each B ds_read); 3-deep LDS ring, counted
// vmcnt(4), single raw s_barrier per phase.
__global__ __launch_bounds__(256, 2) void kern_argmin_mfma(
    const float* __restrict__ xt, const float* __restrict__ cn2h,
    const _Float16* __restrict__ chi, const _Float16* __restrict__ clo,
    const float* __restrict__ xn2, int* __restrict__ idxb,
    unsigned* __restrict__ counts, double* __restrict__ dacc)
{
    __shared__ __align__(16) _Float16 Bs[3][2][8][512];  // 48 KB ring
    __shared__ float cvs[2048];                          // -0.5*||c||^2
    const int tid = threadIdx.x;
    const int w = tid >> 6, lane = tid & 63;
    const int n0 = blockIdx.x * 256 + w * 64;            // 512 blocks
    const int l31 = lane & 31, g = lane >> 5;

    // stage cn2h into LDS (loop-body VMEM must be ONLY the gload_lds)
    for (int i = tid; i < 2048; i += 256) cvs[i] = cn2h[i];

    // A fragments from xt: 2 row-blocks, k = 16s + 4g + {0..3, 8..11}
    f16x8_t ahi[2][4], alo5[2][4];
#pragma unroll
    for (int rb = 0; rb < 2; ++rb) {
        const float* xr = xt + ((size_t)(n0 + rb * 32 + l31) << 6) + 4 * g;
#pragma unroll
        for (int s = 0; s < 4; ++s) {
            float4 p = *(const float4*)(xr + 16 * s);
            float4 q = *(const float4*)(xr + 16 * s + 8);
            float vals[8] = {p.x, p.y, p.z, p.w, q.x, q.y, q.z, q.w};
#pragma unroll
            for (int i = 0; i < 8; ++i) {
                _Float16 h = (_Float16)vals[i];
                ahi[rb][s][i] = h;
                alo5[rb][s][i] = (_Float16)((vals[i] - (float)h) * LO_SCALE5);
            }
        }
    }
    float bestm[2][16]; int besti[2][16];
#pragma unroll
    for (int rb = 0; rb < 2; ++rb)
#pragma unroll
        for (int r = 0; r < 16; ++r) { bestm[rb][r] = -INFINITY; besti[rb][r] = 0; }

    __syncthreads();   // cvs visible; drains all prologue VMEM (vmcnt -> 0)

    // prologue staging: phases 0,1 into ring slots 0,1 (4 segs per wave each)
#pragma unroll
    for (int kt = 0; kt < 2; ++kt)
#pragma unroll
        for (int j = 0; j < 4; ++j) {
            int seg = (j << 2) | w;
            int tt = seg >> 3, sh = seg & 7;
            const _Float16* src = ((sh & 1) ? clo : chi)
                + ((((size_t)(kt * 2 + tt)) * 4 + (sh >> 1)) << 9) + lane * 8;
            gload_lds16(src, &Bs[kt][tt][sh][0]);
        }

    int cur = 0, nxt = 2;
    for (int kt = 0; kt < 32; ++kt) {
        // counted wait: retire this phase's 4 loads, keep next phase's in flight
        if (kt < 30) asm volatile("s_waitcnt vmcnt(4)" ::: "memory");
        else         asm volatile("s_waitcnt vmcnt(0)" ::: "memory");
        __builtin_amdgcn_s_barrier();
        if (kt + 2 < 32) {
#pragma unroll
            for (int j = 0; j < 4; ++j) {
                int seg = (j << 2) | w;
                int tt = seg >> 3, sh = seg & 7;
                const _Float16* src = ((sh & 1) ? clo : chi)
                    + ((((size_t)((kt + 2) * 2 + tt)) * 4 + (sh >> 1)) << 9) + lane * 8;
                gload_lds16(src, &Bs[nxt][tt][sh][0]);
            }
        }
#pragma unroll
        for (int tt = 0; tt < 2; ++tt) {
            const int tg = kt * 2 + tt;
            f16x8_t bh[4], bl[4];
#pragma unroll
            for (int s = 0; s < 4; ++s) {
                bh[s] = *(const f16x8_t*)&Bs[cur][tt][s * 2 + 0][lane * 8];
                bl[s] = *(const f16x8_t*)&Bs[cur][tt][s * 2 + 1][lane * 8];
            }
            float cv = cvs[(tg << 5) + l31];
            f32x16_t a0, a1;
#pragma unroll
            for (int r = 0; r < 16; ++r) { a0[r] = cv; a1[r] = cv; }
#pragma unroll
            for (int s = 0; s < 4; ++s) {
                a0 = __builtin_amdgcn_mfma_f32_32x32x16_f16(ahi[0][s], bh[s], a0, 0, 0, 0);
                a1 = __builtin_amdgcn_mfma_f32_32x32x16_f16(ahi[1][s], bh[s], a1, 0, 0, 0);
                f16x8_t bh5 = bh[s] * (_Float16)0.03125f;   // exact 2^-5
                a0 = __builtin_amdgcn_mfma_f32_32x32x16_f16(alo5[0][s], bh5, a0, 0, 0, 0);
                a1 = __builtin_amdgcn_mfma_f32_32x32x16_f16(alo5[1][s], bh5, a1, 0, 0, 0);
                f16x8_t h50 = ahi[0][s] * (_Float16)0.03125f;
                f16x8_t h51 = ahi[1][s] * (_Float16)0.03125f;
                a0 = __builtin_amdgcn_mfma_f32_32x32x16_f16(h50, bl[s], a0, 0, 0, 0);
                a1 = __builtin_amdgcn_mfma_f32_32x32x16_f16(h51, bl[s], a1, 0, 0, 0);
            }
#pragma unroll
            for (int r = 0; r < 16; ++r) {
                if (a0[r] > bestm[0][r]) { bestm[0][r] = a0[r]; besti[0][r] = tg; }
                if (a1[r] > bestm[1][r]) { bestm[1][r] = a1[r]; besti[1][r] = tg; }
            }
        }
        cur = (cur == 2) ? 0 : cur + 1;
        nxt = (nxt == 2) ? 0 : nxt + 1;
    }
    // cross-lane argmax over the 32 codes (within each 32-lane half)
    float fs = 0.f;
#pragma unroll
    for (int rb = 0; rb < 2; ++rb)
#pragma unroll
        for (int r = 0; r < 16; ++r) {
            float mv = bestm[rb][r]; int mi = (besti[rb][r] << 5) + l31;
#pragma unroll
            for (int m = 1; m < 32; m <<= 1) {
                float ov = __shfl_xor(mv, m, 64);
                int oi = __shfl_xor(mi, m, 64);
                if (ov > mv || (ov == mv && oi < mi)) { mv = ov; mi = oi; }
            }
            if (l31 == 0) {
                int row = (r & 3) + 8 * (r >> 2) + 4 * g;
                int n = n0 + rb * 32 + row;
                idxb[n] = mi;
                atomicAdd(&counts[mi], 1u);
                fs += xn2[n] - 2.f * mv;
            }
        }
    if (l31 == 0) atomicAdd(&dacc[2], (double)fs);
}

// ---------- Kernel S1: exclusive scan of counts -> cursors ------------------
__global__ void kern_scan(const unsigned* __restrict__ counts, unsigned* __restrict__ curs) {
    __shared__ unsigned wtot[4];
    const int tid = threadIdx.x;
    const int base = tid * 8;
    unsigned s[8]; unsigned tot = 0;
#pragma unroll
    for (int j = 0; j < 8; ++j) { s[j] = counts[base + j]; tot += s[j]; }
    unsigned v = tot;
    const int lane = tid & 63;
#pragma unroll
    for (int d = 1; d < 64; d <<= 1) {
        unsigned o = (unsigned)__shfl_up((int)v, d, 64);
        if (lane >= d) v += o;
    }
    if (lane == 63) wtot[tid >> 6] = v;
    __syncthreads();
    unsigned wbase = 0;
    for (int w = 0; w < (tid >> 6); ++w) wbase += wtot[w];
    unsigned run = wbase + v - tot;
#pragma unroll
    for (int j = 0; j < 8; ++j) { curs[base + j] = run; run += s[j]; }
}

// ---------- Kernel S2: scatter packed (code,id) into bins -------------------
__global__ void kern_scatter(const int* __restrict__ idxb, unsigned* __restrict__ curs,
                             unsigned* __restrict__ sorted) {
    const int n = blockIdx.x * 256 + threadIdx.x;   // 512 blocks
    int k = idxb[n];
    unsigned pos = atomicAdd(&curs[k], 1u);
    sorted[pos] = ((unsigned)k << 17) | (unsigned)n;
}

// ---------- Kernel R: chunked segmented reduction -> cb_sum -----------------
__global__ __launch_bounds__(256) void kern_chunk_reduce(
    const float* __restrict__ xt, const unsigned* __restrict__ sorted,
    float* __restrict__ cb_sum)
{
    const int tid = threadIdx.x;
    const int w = tid >> 6, lane = tid & 63;
    const int base = blockIdx.x * 256 + w * 64;
    int kcur = (int)(sorted[base] >> 17);
    float acc = 0.f;
#pragma unroll 4
    for (int it = 0; it < 16; ++it) {
        uint4 p = *(const uint4*)&sorted[base + it * 4];
        float v0 = xt[((size_t)(p.x & 0x1FFFFu) << 6) + lane];
        float v1 = xt[((size_t)(p.y & 0x1FFFFu) << 6) + lane];
        float v2 = xt[((size_t)(p.z & 0x1FFFFu) << 6) + lane];
        float v3 = xt[((size_t)(p.w & 0x1FFFFu) << 6) + lane];
        int k0 = (int)(p.x >> 17), k1 = (int)(p.y >> 17);
        int k2 = (int)(p.z >> 17), k3 = (int)(p.w >> 17);
        if (k0 != kcur) { atomicAdd(&cb_sum[(kcur << 6) + lane], acc); kcur = k0; acc = 0.f; }
        acc += v0;
        if (k1 != kcur) { atomicAdd(&cb_sum[(kcur << 6) + lane], acc); kcur = k1; acc = 0.f; }
        acc += v1;
        if (k2 != kcur) { atomicAdd(&cb_sum[(kcur << 6) + lane], acc); kcur = k2; acc = 0.f; }
        acc += v2;
        if (k3 != kcur) { atomicAdd(&cb_sum[(kcur << 6) + lane], acc); kcur = k3; acc = 0.f; }
        acc += v3;
    }
    atomicAdd(&cb_sum[(kcur << 6) + lane], acc);
}

// ---------- Kernel U: EMA update + keep/replace + diff norm -----------------
__global__ __launch_bounds__(256) void kern_update(
    const float* __restrict__ cb_sum, const unsigned* __restrict__ counts,
    const float* __restrict__ cb, const float* __restrict__ cba,
    const float* __restrict__ usage, const int* __restrict__ perm,
    const float* __restrict__ xt, float* __restrict__ out,
    double* __restrict__ dacc)
{
    const int tid = threadIdx.x;
    const int i = blockIdx.x * 256 + tid;           // 512 blocks
    const int k = i >> 6, e = i & 63;
    float na = 0.99f * cba[i] + 0.01f * cb_sum[i];
    float nu = 0.99f * usage[k] + 0.01f * (float)counts[k];
    float ncb = (nu >= 1.0f) ? (na / nu)
                             : xt[((size_t)perm[k] << 6) + e];
    out[OUT_NAVG + i] = na;
    out[OUT_NCB + i] = ncb;
    if (e == 0) out[OUT_NUSE + k] = nu;
    float d = ncb - cb[i];
    float dd = d * d;
#pragma unroll
    for (int m = 32; m >= 1; m >>= 1) dd += __shfl_xor(dd, m, 64);
    if (e == 0) atomicAdd(&dacc[4], (double)dd);
}

// ---------- Kernel E: scalars (entropy + finalize) --------------------------
// commit = sum min-dist / (N*E) = dacc[2]/8388608 (identical sum to fit).
__global__ void kern_scalars(const unsigned* __restrict__ counts,
                             const double* __restrict__ dacc, float* __restrict__ out) {
    __shared__ float tmp[4];
    __shared__ float totalSh;
    const int tid = threadIdx.x;
    float c = 0.f;
    for (int k = tid; k < 2048; k += 256) c += (float)counts[k];
#pragma unroll
    for (int m = 32; m >= 1; m >>= 1) c += __shfl_xor(c, m, 64);
    if ((tid & 63) == 0) tmp[tid >> 6] = c;
    __syncthreads();
    if (tid == 0) totalSh = tmp[0] + tmp[1] + tmp[2] + tmp[3];
    __syncthreads();
    const float total = totalSh;
    float ent = 0.f;
    for (int k = tid; k < 2048; k += 256) {
        float p = (float)counts[k] / total;
        ent -= p * logf(p + 1e-8f);
    }
#pragma unroll
    for (int m = 32; m >= 1; m >>= 1) ent += __shfl_xor(ent, m, 64);
    __syncthreads();
    if ((tid & 63) == 0) tmp[tid >> 6] = ent;
    __syncthreads();
    if (tid == 0) {
        float entropy = tmp[0] + tmp[1] + tmp[2] + tmp[3];
        out[OUT_COMMIT] = (float)(dacc[2] / 8388608.0);
        out[OUT_FIT]    = (float)(dacc[2] / 131072.0);
        double nd = 8388608.0;
        double var = dacc[1] - dacc[0] * dacc[0] / nd;
        if (var < 0.0) var = 0.0;
        out[OUT_XNORM] = (float)(sqrt(var) / sqrt(nd));
        out[OUT_ENT] = entropy;
        out[OUT_CBDIFF] = (float)(sqrt(dacc[4]) / sqrt(131072.0));
    }
}

// ---------- Kernel C: pure gather q -> out (out = q exactly) ----------------
__global__ __launch_bounds__(256) void kern_out(
    const float* __restrict__ cb, const int* __restrict__ idxb,
    float* __restrict__ out) {
    const int tid = threadIdx.x;
    const int n0 = blockIdx.x * 256 + (tid & 63) * 4;   // 512 blocks
    const int ec = tid >> 6;
    const int b = n0 >> 12, t = n0 & 4095;
    int4 k4 = *(const int4*)(idxb + n0);
    float* ob = out + OUT_X + ((size_t)b << 18) + t;
#pragma unroll
    for (int j = 0; j < 16; ++j) {
        int e = ec * 16 + j;
        float q0 = cb[((size_t)k4.x << 6) + e], q1 = cb[((size_t)k4.y << 6) + e];
        float q2 = cb[((size_t)k4.z << 6) + e], q3 = cb[((size_t)k4.w << 6) + e];
        *(float4*)(ob + ((size_t)e << 12)) = make_float4(q0, q1, q2, q3);
    }
}

extern "C" void kernel_launch(void* const* d_in, const int* in_sizes, int n_in,
                              void* d_out, int out_size, void* d_ws, size_t ws_size,
                              hipStream_t stream) {
    const float* x     = (const float*)d_in[0];
    const float* cb    = (const float*)d_in[1];
    const float* cba   = (const float*)d_in[2];
    const float* usage = (const float*)d_in[3];
    const int*   perm  = (const int*)d_in[4];
    float* out = (float*)d_out;
    char* ws = (char*)d_ws;
    double*    dacc   = (double*)(ws + WS_DACC);
    unsigned*  counts = (unsigned*)(ws + WS_COUNTS);
    float*     cbsum  = (float*)(ws + WS_CBSUM);
    unsigned*  curs   = (unsigned*)(ws + WS_CURS);
    float*     xn2    = (float*)(ws + WS_XN2);
    int*       idxb   = (int*)(ws + WS_IDX);
    float*     cn2h   = (float*)(ws + WS_CN2H);
    unsigned*  sorted = (unsigned*)(ws + WS_SORTED);
    _Float16*  chi    = (_Float16*)(ws + WS_CHI);
    _Float16*  clo    = (_Float16*)(ws + WS_CLO);
    float*     xt     = out + OUT_X;   // staged; overwritten last by kern_out

    hipMemsetAsync(ws, 0, WS_ZERO_BYTES, stream);
    kern_prep<<<1040, 256, 0, stream>>>(x, xt, xn2, dacc, cb, chi, clo, cn2h);
    kern_argmin_mfma<<<512, 256, 0, stream>>>(xt, cn2h, chi, clo, xn2, idxb, counts, dacc);
    kern_scan<<<1, 256, 0, stream>>>(counts, curs);
    kern_scatter<<<512, 256, 0, stream>>>(idxb, curs, sorted);
    kern_chunk_reduce<<<512, 256, 0, stream>>>(xt, sorted, cbsum);
    kern_update<<<512, 256, 0, stream>>>(cbsum, counts, cb, cba, usage, perm, xt, out, dacc);
    kern_scalars<<<1, 256, 0, stream>>>(counts, dacc, out);
    kern_out<<<512, 256, 0, stream>>>(cb, idxb, out);
}